// Round 1
// baseline (69.417 us; speedup 1.0000x reference)
//
#include <hip/hip_runtime.h>

// Problem constants (B,S,D)=(2048,64,128), H=8, DK=16, F=128, temp=4
#define B_ 2048
#define S_ 64
#define D_ 128
#define F_ 128
#define H_ 8

// ---------------------------------------------------------------------------
// K1: per batch row b: vbar = mean_s v[b,s,:]; q1[b,:] = vbar @ Wq^T + bq
// grid 2048 x 256
// ---------------------------------------------------------------------------
__global__ __launch_bounds__(256) void k_q1(const float* __restrict__ v,
                                            const float* __restrict__ Wq,
                                            const float* __restrict__ bq,
                                            float* __restrict__ q1) {
  const int b = blockIdx.x;
  const int t = threadIdx.x;
  __shared__ float red[8 * 128];
  __shared__ __align__(16) float vbarL[128];

  const int c4 = t & 31;      // float4 column
  const int r0 = t >> 5;      // row stripe (8 stripes x 8 rows)
  const float4* v4 = (const float4*)(v + (size_t)b * (S_ * D_));
  float4 acc = {0.f, 0.f, 0.f, 0.f};
  #pragma unroll
  for (int i = 0; i < 8; ++i) {
    float4 x = v4[(r0 * 8 + i) * 32 + c4];
    acc.x += x.x; acc.y += x.y; acc.z += x.z; acc.w += x.w;
  }
  red[r0 * 128 + c4 * 4 + 0] = acc.x;
  red[r0 * 128 + c4 * 4 + 1] = acc.y;
  red[r0 * 128 + c4 * 4 + 2] = acc.z;
  red[r0 * 128 + c4 * 4 + 3] = acc.w;
  __syncthreads();
  if (t < 128) {
    float s = 0.f;
    #pragma unroll
    for (int r = 0; r < 8; ++r) s += red[r * 128 + t];
    vbarL[t] = s * (1.0f / 64.0f);
  }
  __syncthreads();

  // q1[b,f] = dot(vbar, Wq[f,:]) + bq[f]; 32 lanes per f, shuffle-reduced
  const float4* Wq4 = (const float4*)Wq;
  const float4* vb4 = (const float4*)vbarL;
  const int d4 = t & 31;
  const int fg = t >> 5;  // 8 f-groups per iteration
  #pragma unroll
  for (int fi = 0; fi < 16; ++fi) {
    int f = fi * 8 + fg;
    float4 w = Wq4[f * 32 + d4];
    float4 vv = vb4[d4];
    float p = w.x * vv.x + w.y * vv.y + w.z * vv.z + w.w * vv.w;
    #pragma unroll
    for (int off = 16; off; off >>= 1) p += __shfl_down(p, off, 32);
    if (d4 == 0) q1[b * F_ + f] = p + bq[f];
  }
}

// ---------------------------------------------------------------------------
// K2: BatchNorm batch stats per feature -> fused scale/shift
// grid 128 x 256 (block = feature)
// ---------------------------------------------------------------------------
__global__ __launch_bounds__(256) void k_stats(const float* __restrict__ q1,
                                               const float* __restrict__ gamma,
                                               const float* __restrict__ beta,
                                               float* __restrict__ sscale,
                                               float* __restrict__ sshift) {
  const int f = blockIdx.x;
  const int t = threadIdx.x;
  float s = 0.f, sq = 0.f;
  #pragma unroll
  for (int i = 0; i < 8; ++i) {
    float x = q1[(i * 256 + t) * F_ + f];
    s += x;
    sq += x * x;
  }
  #pragma unroll
  for (int off = 32; off; off >>= 1) {
    s += __shfl_down(s, off, 64);
    sq += __shfl_down(sq, off, 64);
  }
  __shared__ float rs_[4], rq_[4];
  const int w = t >> 6;
  if ((t & 63) == 0) { rs_[w] = s; rq_[w] = sq; }
  __syncthreads();
  if (t == 0) {
    s = rs_[0] + rs_[1] + rs_[2] + rs_[3];
    sq = rq_[0] + rq_[1] + rq_[2] + rq_[3];
    float mu = s * (1.0f / (float)B_);
    float var = sq * (1.0f / (float)B_) - mu * mu;
    float rsg = rsqrtf(var + 1e-5f) * gamma[f];
    sscale[f] = rsg;
    sshift[f] = beta[f] - mu * rsg;
  }
}

// ---------------------------------------------------------------------------
// K3: qn = BN(q1); q2 = qn @ W2^T + b2; qW[b,h,:] = sum_dk q2[h*16+dk]*Wk row;
//     qb[b,h] = sum_dk q2[h*16+dk]*bk.   grid 256 x 256, 8 batch rows / block
// ---------------------------------------------------------------------------
__global__ __launch_bounds__(256) void k_qw(const float* __restrict__ q1,
                                            const float* __restrict__ sscale,
                                            const float* __restrict__ sshift,
                                            const float* __restrict__ W2,
                                            const float* __restrict__ b2,
                                            const float* __restrict__ Wk,
                                            const float* __restrict__ bk,
                                            float* __restrict__ qW,
                                            float* __restrict__ qb) {
  const int b0 = blockIdx.x * 8;
  const int t = threadIdx.x;
  __shared__ __align__(16) float W2L[128 * 128];  // XOR-swizzled at float4 level
  __shared__ __align__(16) float qnL[8 * 128];
  __shared__ __align__(16) float q2L[8 * 128];

  float4* W2L4 = (float4*)W2L;
  const float4* W2g4 = (const float4*)W2;
  #pragma unroll
  for (int i = 0; i < 16; ++i) {
    int idx4 = i * 256 + t;            // 4096 float4s
    int g = idx4 >> 5, f4 = idx4 & 31;
    W2L4[g * 32 + (f4 ^ (g & 31))] = W2g4[idx4];
  }
  #pragma unroll
  for (int i = 0; i < 4; ++i) {
    int idx = i * 256 + t;             // 1024 floats
    int bi = idx >> 7, f = idx & 127;
    qnL[idx] = q1[(b0 + bi) * F_ + f] * sscale[f] + sshift[f];
  }
  __syncthreads();

  const float4* qnL4 = (const float4*)qnL;
  #pragma unroll
  for (int i = 0; i < 4; ++i) {
    int o = i * 256 + t;               // 1024 outputs
    int bi = o >> 7, g = o & 127;
    float acc = b2[g];
    #pragma unroll
    for (int f4 = 0; f4 < 32; ++f4) {
      float4 qv = qnL4[bi * 32 + f4];
      float4 wv = W2L4[g * 32 + (f4 ^ (g & 31))];
      acc += qv.x * wv.x + qv.y * wv.y + qv.z * wv.z + qv.w * wv.w;
    }
    q2L[bi * 128 + g] = acc;
  }
  __syncthreads();

  const float4* Wk4 = (const float4*)Wk;
  #pragma unroll
  for (int i = 0; i < 8; ++i) {
    int o4 = i * 256 + t;              // 2048 float4 outputs
    int bi = o4 >> 8, h = (o4 >> 5) & 7, d4 = o4 & 31;
    float4 acc = {0.f, 0.f, 0.f, 0.f};
    const float* q2row = &q2L[bi * 128 + h * 16];
    #pragma unroll
    for (int dk = 0; dk < 16; ++dk) {
      float q = q2row[dk];
      float4 w = Wk4[(h * 16 + dk) * 32 + d4];
      acc.x += q * w.x; acc.y += q * w.y; acc.z += q * w.z; acc.w += q * w.w;
    }
    ((float4*)qW)[(size_t)(b0 + bi) * 256 + h * 32 + d4] = acc;
  }
  if (t < 64) {
    int bi = t >> 3, h = t & 7;
    float acc = 0.f;
    #pragma unroll
    for (int dk = 0; dk < 16; ++dk)
      acc += q2L[bi * 128 + h * 16 + dk] * bk[h * 16 + dk];
    qb[(b0 + bi) * 8 + h] = acc;
  }
}

// ---------------------------------------------------------------------------
// K4: per batch row: stage v[b] in swizzled LDS; logits = qW.v + qb (/4);
//     wave-wide softmax (one wave = 2 heads, lane = s); out = attn @ v.
// grid 2048 x 256
// ---------------------------------------------------------------------------
__global__ __launch_bounds__(256) void k_attn(const float* __restrict__ v,
                                              const float* __restrict__ qW,
                                              const float* __restrict__ qb,
                                              float* __restrict__ outp) {
  const int b = blockIdx.x;
  const int t = threadIdx.x;
  __shared__ __align__(16) float vL[64 * 128];   // XOR-swizzled float4 rows
  __shared__ __align__(16) float qWL[8 * 128];
  __shared__ float attnL[8 * 64];
  __shared__ float qbL[8];

  float4* vL4 = (float4*)vL;
  const float4* vg4 = (const float4*)(v + (size_t)b * (S_ * D_));
  #pragma unroll
  for (int i = 0; i < 8; ++i) {
    int idx = i * 256 + t;             // 2048 float4s
    int s = idx >> 5, c4 = idx & 31;
    vL4[s * 32 + (c4 ^ (s & 31))] = vg4[idx];
  }
  {
    const float4* qWg4 = (const float4*)(qW + (size_t)b * (H_ * D_));
    ((float4*)qWL)[t] = qWg4[t];       // 256 float4 = 1024 floats
  }
  if (t < 8) qbL[t] = qb[b * 8 + t];
  __syncthreads();

  // logits: thread -> (s = t&63, heads 2*hq and 2*hq+1)
  const int s = t & 63;
  const int hq = t >> 6;
  const int h0 = hq * 2, h1 = hq * 2 + 1;
  const float4* qWL4 = (const float4*)qWL;
  float a0 = 0.f, a1 = 0.f;
  #pragma unroll
  for (int d4 = 0; d4 < 32; ++d4) {
    float4 vv = vL4[s * 32 + (d4 ^ (s & 31))];
    float4 w0 = qWL4[h0 * 32 + d4];
    float4 w1 = qWL4[h1 * 32 + d4];
    a0 += vv.x * w0.x + vv.y * w0.y + vv.z * w0.z + vv.w * w0.w;
    a1 += vv.x * w1.x + vv.y * w1.y + vv.z * w1.z + vv.w * w1.w;
  }
  float l0 = (a0 + qbL[h0]) * 0.25f;   // temperature = sqrt(16) = 4
  float l1 = (a1 + qbL[h1]) * 0.25f;

  // softmax across the 64 lanes of this wave (lane == s)
  float m0 = l0, m1 = l1;
  #pragma unroll
  for (int off = 32; off; off >>= 1) {
    m0 = fmaxf(m0, __shfl_xor(m0, off, 64));
    m1 = fmaxf(m1, __shfl_xor(m1, off, 64));
  }
  float e0 = __expf(l0 - m0), e1 = __expf(l1 - m1);
  float s0 = e0, s1 = e1;
  #pragma unroll
  for (int off = 32; off; off >>= 1) {
    s0 += __shfl_xor(s0, off, 64);
    s1 += __shfl_xor(s1, off, 64);
  }
  float at0 = e0 / s0, at1 = e1 / s1;
  attnL[h0 * 64 + s] = at0;
  attnL[h1 * 64 + s] = at1;
  float* attn_out = outp + (size_t)H_ * B_ * D_;
  attn_out[(size_t)h0 * (B_ * S_) + b * S_ + s] = at0;
  attn_out[(size_t)h1 * (B_ * S_) + b * S_ + s] = at1;
  __syncthreads();

  // out[h, b, :] = sum_s attn[h,s] * v[b,s,:]; thread -> (h = t>>5, d4 = t&31)
  const int d4o = t & 31;
  const int h = t >> 5;
  float4 acc = {0.f, 0.f, 0.f, 0.f};
  #pragma unroll
  for (int si = 0; si < 64; ++si) {
    float a = attnL[h * 64 + si];
    float4 vv = vL4[si * 32 + (d4o ^ (si & 31))];
    acc.x += a * vv.x; acc.y += a * vv.y; acc.z += a * vv.z; acc.w += a * vv.w;
  }
  ((float4*)outp)[(size_t)h * (B_ * 32) + b * 32 + d4o] = acc;
}

// ---------------------------------------------------------------------------
extern "C" void kernel_launch(void* const* d_in, const int* in_sizes, int n_in,
                              void* d_out, int out_size, void* d_ws, size_t ws_size,
                              hipStream_t stream) {
  const float* v     = (const float*)d_in[0];
  const float* Wq    = (const float*)d_in[1];
  const float* bq    = (const float*)d_in[2];
  const float* gamma = (const float*)d_in[3];
  const float* beta  = (const float*)d_in[4];
  const float* W2    = (const float*)d_in[5];
  const float* b2    = (const float*)d_in[6];
  const float* Wk    = (const float*)d_in[7];
  const float* bk    = (const float*)d_in[8];

  float* ws = (float*)d_ws;
  // ws layout (floats): q1[B*F] | sscale[128] | sshift[128] | qW[B*H*D] | qb[B*H]
  float* q1v    = ws;
  float* sscale = ws + (size_t)B_ * F_;            // 262144
  float* sshift = sscale + 128;                    // 262272
  float* qWv    = sshift + 128;                    // 262400
  float* qbv    = qWv + (size_t)B_ * H_ * D_;      // 2359552
  float* outp   = (float*)d_out;

  hipLaunchKernelGGL(k_q1,    dim3(B_),  dim3(256), 0, stream, v, Wq, bq, q1v);
  hipLaunchKernelGGL(k_stats, dim3(F_),  dim3(256), 0, stream, q1v, gamma, beta, sscale, sshift);
  hipLaunchKernelGGL(k_qw,    dim3(256), dim3(256), 0, stream, q1v, sscale, sshift, W2, b2, Wk, bk, qWv, qbv);
  hipLaunchKernelGGL(k_attn,  dim3(B_),  dim3(256), 0, stream, v, qWv, qbv, outp);
}

// Round 2
// 65.227 us; speedup vs baseline: 1.0642x; 1.0642x over previous
//
#include <hip/hip_runtime.h>

// Problem constants (B,S,D)=(2048,64,128), H=8, DK=16, F=128, temp=4
#define B_ 2048
#define S_ 64
#define D_ 128
#define F_ 128
#define H_ 8

// ---------------------------------------------------------------------------
// K1: per batch row b: vbar = mean_s v[b,s,:]; q1[b,:] = vbar @ Wq^T + bq
// grid 2048 x 256
// ---------------------------------------------------------------------------
__global__ __launch_bounds__(256) void k_q1(const float* __restrict__ v,
                                            const float* __restrict__ Wq,
                                            const float* __restrict__ bq,
                                            float* __restrict__ q1) {
  const int b = blockIdx.x;
  const int t = threadIdx.x;
  __shared__ float red[8 * 128];
  __shared__ __align__(16) float vbarL[128];

  const int c4 = t & 31;      // float4 column
  const int r0 = t >> 5;      // row stripe (8 stripes x 8 rows)
  const float4* v4 = (const float4*)(v + (size_t)b * (S_ * D_));
  float4 acc = {0.f, 0.f, 0.f, 0.f};
  #pragma unroll
  for (int i = 0; i < 8; ++i) {
    float4 x = v4[(r0 * 8 + i) * 32 + c4];
    acc.x += x.x; acc.y += x.y; acc.z += x.z; acc.w += x.w;
  }
  red[r0 * 128 + c4 * 4 + 0] = acc.x;
  red[r0 * 128 + c4 * 4 + 1] = acc.y;
  red[r0 * 128 + c4 * 4 + 2] = acc.z;
  red[r0 * 128 + c4 * 4 + 3] = acc.w;
  __syncthreads();
  if (t < 128) {
    float s = 0.f;
    #pragma unroll
    for (int r = 0; r < 8; ++r) s += red[r * 128 + t];
    vbarL[t] = s * (1.0f / 64.0f);
  }
  __syncthreads();

  // q1[b,f] = dot(vbar, Wq[f,:]) + bq[f]; 32 lanes per f, shuffle-reduced
  const float4* Wq4 = (const float4*)Wq;
  const float4* vb4 = (const float4*)vbarL;
  const int d4 = t & 31;
  const int fg = t >> 5;  // 8 f-groups per iteration
  #pragma unroll
  for (int fi = 0; fi < 16; ++fi) {
    int f = fi * 8 + fg;
    float4 w = Wq4[f * 32 + d4];
    float4 vv = vb4[d4];
    float p = w.x * vv.x + w.y * vv.y + w.z * vv.z + w.w * vv.w;
    #pragma unroll
    for (int off = 16; off; off >>= 1) p += __shfl_down(p, off, 32);
    if (d4 == 0) q1[b * F_ + f] = p + bq[f];
  }
}

// ---------------------------------------------------------------------------
// K2: coalesced BN partial sums (atomicAdd into zeroed gsum/gsq) + W2
// transpose.  grid 64 x 256; block i handles rows [i*32, i*32+32) and
// transposes W2 rows g = 2i, 2i+1.
// ---------------------------------------------------------------------------
__global__ __launch_bounds__(256) void k_stats2(const float* __restrict__ q1,
                                                const float* __restrict__ W2,
                                                float* __restrict__ gsum,
                                                float* __restrict__ gsq,
                                                float* __restrict__ W2t) {
  const int blk = blockIdx.x;
  const int t = threadIdx.x;
  const int f4 = t & 31, rg = t >> 5;
  const int r0 = blk * 32;
  const float4* q14 = (const float4*)q1;
  float4 s = {0.f, 0.f, 0.f, 0.f};
  float4 q = {0.f, 0.f, 0.f, 0.f};
  #pragma unroll
  for (int k = 0; k < 4; ++k) {
    float4 x = q14[(size_t)(r0 + rg + 8 * k) * 32 + f4];
    s.x += x.x; s.y += x.y; s.z += x.z; s.w += x.w;
    q.x += x.x * x.x; q.y += x.y * x.y; q.z += x.z * x.z; q.w += x.w * x.w;
  }
  __shared__ float rs[8][128], rq[8][128];
  rs[rg][f4 * 4 + 0] = s.x; rs[rg][f4 * 4 + 1] = s.y;
  rs[rg][f4 * 4 + 2] = s.z; rs[rg][f4 * 4 + 3] = s.w;
  rq[rg][f4 * 4 + 0] = q.x; rq[rg][f4 * 4 + 1] = q.y;
  rq[rg][f4 * 4 + 2] = q.z; rq[rg][f4 * 4 + 3] = q.w;
  __syncthreads();
  if (t < 128) {
    float ss = 0.f, qq = 0.f;
    #pragma unroll
    for (int r = 0; r < 8; ++r) { ss += rs[r][t]; qq += rq[r][t]; }
    atomicAdd(&gsum[t], ss);
    atomicAdd(&gsq[t], qq);
  }
  // W2 transpose: W2t[f][g] = W2[g][f]
  {
    int g = blk * 2 + (t >> 7);
    int f = t & 127;
    W2t[f * 128 + g] = W2[g * 128 + f];
  }
}

// ---------------------------------------------------------------------------
// K3: per block: compute BN scale/shift from sums (redundant, cheap);
// qn = BN(q1); q2 = qn @ W2^T + b2 using W2t with coalesced float4 loads.
// grid 256 x 256; 8 batch rows per block, thread = (row, 4-col group).
// ---------------------------------------------------------------------------
__global__ __launch_bounds__(256) void k_q2(const float* __restrict__ q1,
                                            const float* __restrict__ gsum,
                                            const float* __restrict__ gsq,
                                            const float* __restrict__ gamma,
                                            const float* __restrict__ beta,
                                            const float* __restrict__ W2t,
                                            const float* __restrict__ b2,
                                            float* __restrict__ q2) {
  const int b0 = blockIdx.x * 8;
  const int t = threadIdx.x;
  __shared__ float scaleL[128], shiftL[128];
  __shared__ __align__(16) float qnL[8 * 128];

  if (t < 128) {
    float mu = gsum[t] * (1.0f / (float)B_);
    float var = gsq[t] * (1.0f / (float)B_) - mu * mu;
    float rsg = rsqrtf(var + 1e-5f) * gamma[t];
    scaleL[t] = rsg;
    shiftL[t] = beta[t] - mu * rsg;
  }
  __syncthreads();
  {
    int row = t >> 5, f4 = t & 31;
    float4 x = ((const float4*)q1)[(size_t)(b0 + row) * 32 + f4];
    x.x = x.x * scaleL[f4 * 4 + 0] + shiftL[f4 * 4 + 0];
    x.y = x.y * scaleL[f4 * 4 + 1] + shiftL[f4 * 4 + 1];
    x.z = x.z * scaleL[f4 * 4 + 2] + shiftL[f4 * 4 + 2];
    x.w = x.w * scaleL[f4 * 4 + 3] + shiftL[f4 * 4 + 3];
    ((float4*)qnL)[row * 32 + f4] = x;
  }
  __syncthreads();

  const int r = t >> 5, g4 = t & 31;
  const float4* W2t4 = (const float4*)W2t;
  float4 acc = ((const float4*)b2)[g4];
  #pragma unroll 8
  for (int f = 0; f < 128; ++f) {
    float4 w = W2t4[f * 32 + g4];
    float qv = qnL[r * 128 + f];
    acc.x += qv * w.x; acc.y += qv * w.y; acc.z += qv * w.z; acc.w += qv * w.w;
  }
  ((float4*)q2)[(size_t)(b0 + r) * 32 + g4] = acc;
}

// ---------------------------------------------------------------------------
// K4: per batch row: stage v[b] swizzled in LDS; qW[h,:] = q2-slice @ Wk_h
// (fused, Wk L2-hot); logits = qW.v + qb (/4); wave-wide softmax; out.
// grid 2048 x 256
// ---------------------------------------------------------------------------
__global__ __launch_bounds__(256) void k_attn(const float* __restrict__ v,
                                              const float* __restrict__ q2,
                                              const float* __restrict__ Wk,
                                              const float* __restrict__ bk,
                                              float* __restrict__ outp) {
  const int b = blockIdx.x;
  const int t = threadIdx.x;
  __shared__ __align__(16) float vL[64 * 128];   // XOR-swizzled float4 rows
  __shared__ __align__(16) float qWL[8 * 128];
  __shared__ __align__(16) float q2L[128];
  __shared__ float attnL[8 * 64];
  __shared__ float qbL[8];

  float4* vL4 = (float4*)vL;
  const float4* vg4 = (const float4*)(v + (size_t)b * (S_ * D_));
  #pragma unroll
  for (int i = 0; i < 8; ++i) {
    int idx = i * 256 + t;             // 2048 float4s
    int s = idx >> 5, c4 = idx & 31;
    vL4[s * 32 + (c4 ^ (s & 31))] = vg4[idx];
  }
  if (t < 32) ((float4*)q2L)[t] = ((const float4*)q2)[(size_t)b * 32 + t];
  __syncthreads();

  // qW[h,d] = sum_dk q2[h*16+dk] * Wk[h*16+dk, d]
  {
    const int h = t >> 5, d4 = t & 31;
    const float4* Wk4 = (const float4*)Wk;
    const float* q2row = &q2L[h * 16];
    float4 acc = {0.f, 0.f, 0.f, 0.f};
    #pragma unroll
    for (int dk = 0; dk < 16; ++dk) {
      float qv = q2row[dk];
      float4 w = Wk4[(h * 16 + dk) * 32 + d4];
      acc.x += qv * w.x; acc.y += qv * w.y; acc.z += qv * w.z; acc.w += qv * w.w;
    }
    ((float4*)qWL)[h * 32 + d4] = acc;
  }
  if (t < 8) {
    float acc = 0.f;
    #pragma unroll
    for (int dk = 0; dk < 16; ++dk)
      acc += q2L[t * 16 + dk] * bk[t * 16 + dk];
    qbL[t] = acc;
  }
  __syncthreads();

  // logits: thread -> (s = t&63, heads 2*hq and 2*hq+1)
  const int s = t & 63;
  const int hq = t >> 6;
  const int h0 = hq * 2, h1 = hq * 2 + 1;
  const float4* qWL4 = (const float4*)qWL;
  float a0 = 0.f, a1 = 0.f;
  #pragma unroll
  for (int d4 = 0; d4 < 32; ++d4) {
    float4 vv = vL4[s * 32 + (d4 ^ (s & 31))];
    float4 w0 = qWL4[h0 * 32 + d4];
    float4 w1 = qWL4[h1 * 32 + d4];
    a0 += vv.x * w0.x + vv.y * w0.y + vv.z * w0.z + vv.w * w0.w;
    a1 += vv.x * w1.x + vv.y * w1.y + vv.z * w1.z + vv.w * w1.w;
  }
  float l0 = (a0 + qbL[h0]) * 0.25f;   // temperature = sqrt(16) = 4
  float l1 = (a1 + qbL[h1]) * 0.25f;

  // softmax across the 64 lanes of this wave (lane == s)
  float m0 = l0, m1 = l1;
  #pragma unroll
  for (int off = 32; off; off >>= 1) {
    m0 = fmaxf(m0, __shfl_xor(m0, off, 64));
    m1 = fmaxf(m1, __shfl_xor(m1, off, 64));
  }
  float e0 = __expf(l0 - m0), e1 = __expf(l1 - m1);
  float s0 = e0, s1 = e1;
  #pragma unroll
  for (int off = 32; off; off >>= 1) {
    s0 += __shfl_xor(s0, off, 64);
    s1 += __shfl_xor(s1, off, 64);
  }
  float at0 = e0 / s0, at1 = e1 / s1;
  attnL[h0 * 64 + s] = at0;
  attnL[h1 * 64 + s] = at1;
  float* attn_out = outp + (size_t)H_ * B_ * D_;
  attn_out[(size_t)h0 * (B_ * S_) + b * S_ + s] = at0;
  attn_out[(size_t)h1 * (B_ * S_) + b * S_ + s] = at1;
  __syncthreads();

  // out[h, b, :] = sum_s attn[h,s] * v[b,s,:]; thread -> (h = t>>5, d4 = t&31)
  const int d4o = t & 31;
  const int h = t >> 5;
  float4 acc = {0.f, 0.f, 0.f, 0.f};
  #pragma unroll
  for (int si = 0; si < 64; ++si) {
    float a = attnL[h * 64 + si];
    float4 vv = vL4[si * 32 + (d4o ^ (si & 31))];
    acc.x += a * vv.x; acc.y += a * vv.y; acc.z += a * vv.z; acc.w += a * vv.w;
  }
  ((float4*)outp)[(size_t)h * (B_ * 32) + b * 32 + d4o] = acc;
}

// ---------------------------------------------------------------------------
extern "C" void kernel_launch(void* const* d_in, const int* in_sizes, int n_in,
                              void* d_out, int out_size, void* d_ws, size_t ws_size,
                              hipStream_t stream) {
  const float* v     = (const float*)d_in[0];
  const float* Wq    = (const float*)d_in[1];
  const float* bq    = (const float*)d_in[2];
  const float* gamma = (const float*)d_in[3];
  const float* beta  = (const float*)d_in[4];
  const float* W2    = (const float*)d_in[5];
  const float* b2    = (const float*)d_in[6];
  const float* Wk    = (const float*)d_in[7];
  const float* bk    = (const float*)d_in[8];

  float* ws = (float*)d_ws;
  // ws layout (floats): q1[B*F] | q2[B*F] | gsum[128] | gsq[128] | W2t[128*128]
  float* q1v  = ws;                                  // 262144
  float* q2v  = q1v + (size_t)B_ * F_;               // 262144
  float* gsum = q2v + (size_t)B_ * F_;               // 128
  float* gsq  = gsum + 128;                          // 128
  float* W2t  = gsq + 128;                           // 16384
  float* outp = (float*)d_out;

  hipMemsetAsync(gsum, 0, 2 * 128 * sizeof(float), stream);
  hipLaunchKernelGGL(k_q1,     dim3(B_),  dim3(256), 0, stream, v, Wq, bq, q1v);
  hipLaunchKernelGGL(k_stats2, dim3(64),  dim3(256), 0, stream, q1v, W2, gsum, gsq, W2t);
  hipLaunchKernelGGL(k_q2,     dim3(256), dim3(256), 0, stream, q1v, gsum, gsq, gamma, beta, W2t, b2, q2v);
  hipLaunchKernelGGL(k_attn,   dim3(B_),  dim3(256), 0, stream, v, q2v, Wk, bk, outp);
}

// Round 3
// 59.980 us; speedup vs baseline: 1.1573x; 1.0875x over previous
//
#include <hip/hip_runtime.h>

// Problem constants (B,S,D)=(2048,64,128), H=8, DK=16, F=128, temp=4
#define B_ 2048
#define S_ 64
#define D_ 128
#define F_ 128
#define H_ 8

// ---------------------------------------------------------------------------
// K1: per batch row b: vbar = mean_s v[b,s,:]; q1[b,:] = vbar @ Wq^T + bq
// Block 0 also zeroes gsum/gsq (256 contiguous floats) for K2's atomics —
// stream order guarantees K1 completes before K2 starts.
// grid 2048 x 256
// ---------------------------------------------------------------------------
__global__ __launch_bounds__(256) void k_q1(const float* __restrict__ v,
                                            const float* __restrict__ Wq,
                                            const float* __restrict__ bq,
                                            float* __restrict__ q1,
                                            float* __restrict__ gsum) {
  const int b = blockIdx.x;
  const int t = threadIdx.x;
  if (b == 0) gsum[t] = 0.f;   // gsum[128] | gsq[128] contiguous

  __shared__ float red[8 * 128];
  __shared__ __align__(16) float vbarL[128];

  const int c4 = t & 31;      // float4 column
  const int r0 = t >> 5;      // row stripe (8 stripes x 8 rows)
  const float4* v4 = (const float4*)(v + (size_t)b * (S_ * D_));
  float4 acc = {0.f, 0.f, 0.f, 0.f};
  #pragma unroll
  for (int i = 0; i < 8; ++i) {
    float4 x = v4[(r0 * 8 + i) * 32 + c4];
    acc.x += x.x; acc.y += x.y; acc.z += x.z; acc.w += x.w;
  }
  red[r0 * 128 + c4 * 4 + 0] = acc.x;
  red[r0 * 128 + c4 * 4 + 1] = acc.y;
  red[r0 * 128 + c4 * 4 + 2] = acc.z;
  red[r0 * 128 + c4 * 4 + 3] = acc.w;
  __syncthreads();
  if (t < 128) {
    float s = 0.f;
    #pragma unroll
    for (int r = 0; r < 8; ++r) s += red[r * 128 + t];
    vbarL[t] = s * (1.0f / 64.0f);
  }
  __syncthreads();

  // q1[b,f] = dot(vbar, Wq[f,:]) + bq[f]; 32 lanes per f, shuffle-reduced
  const float4* Wq4 = (const float4*)Wq;
  const float4* vb4 = (const float4*)vbarL;
  const int d4 = t & 31;
  const int fg = t >> 5;  // 8 f-groups per iteration
  #pragma unroll
  for (int fi = 0; fi < 16; ++fi) {
    int f = fi * 8 + fg;
    float4 w = Wq4[f * 32 + d4];
    float4 vv = vb4[d4];
    float p = w.x * vv.x + w.y * vv.y + w.z * vv.z + w.w * vv.w;
    #pragma unroll
    for (int off = 16; off; off >>= 1) p += __shfl_down(p, off, 32);
    if (d4 == 0) q1[b * F_ + f] = p + bq[f];
  }
}

// ---------------------------------------------------------------------------
// K2: coalesced BN partial sums (atomicAdd into zeroed gsum/gsq) + W2
// transpose.  grid 64 x 256; block i handles rows [i*32, i*32+32) and
// transposes W2 rows g = 2i, 2i+1.
// ---------------------------------------------------------------------------
__global__ __launch_bounds__(256) void k_stats2(const float* __restrict__ q1,
                                                const float* __restrict__ W2,
                                                float* __restrict__ gsum,
                                                float* __restrict__ gsq,
                                                float* __restrict__ W2t) {
  const int blk = blockIdx.x;
  const int t = threadIdx.x;
  const int f4 = t & 31, rg = t >> 5;
  const int r0 = blk * 32;
  const float4* q14 = (const float4*)q1;
  float4 s = {0.f, 0.f, 0.f, 0.f};
  float4 q = {0.f, 0.f, 0.f, 0.f};
  #pragma unroll
  for (int k = 0; k < 4; ++k) {
    float4 x = q14[(size_t)(r0 + rg + 8 * k) * 32 + f4];
    s.x += x.x; s.y += x.y; s.z += x.z; s.w += x.w;
    q.x += x.x * x.x; q.y += x.y * x.y; q.z += x.z * x.z; q.w += x.w * x.w;
  }
  __shared__ float rs[8][128], rq[8][128];
  rs[rg][f4 * 4 + 0] = s.x; rs[rg][f4 * 4 + 1] = s.y;
  rs[rg][f4 * 4 + 2] = s.z; rs[rg][f4 * 4 + 3] = s.w;
  rq[rg][f4 * 4 + 0] = q.x; rq[rg][f4 * 4 + 1] = q.y;
  rq[rg][f4 * 4 + 2] = q.z; rq[rg][f4 * 4 + 3] = q.w;
  __syncthreads();
  if (t < 128) {
    float ss = 0.f, qq = 0.f;
    #pragma unroll
    for (int r = 0; r < 8; ++r) { ss += rs[r][t]; qq += rq[r][t]; }
    atomicAdd(&gsum[t], ss);
    atomicAdd(&gsq[t], qq);
  }
  // W2 transpose: W2t[f][g] = W2[g][f]
  {
    int g = blk * 2 + (t >> 7);
    int f = t & 127;
    W2t[f * 128 + g] = W2[g * 128 + f];
  }
}

// ---------------------------------------------------------------------------
// K3: per block: compute BN scale/shift from sums (redundant, cheap);
// qn = BN(q1); q2 = qn @ W2^T + b2 using W2t with coalesced float4 loads.
// grid 256 x 256; 8 batch rows per block, thread = (row, 4-col group).
// ---------------------------------------------------------------------------
__global__ __launch_bounds__(256) void k_q2(const float* __restrict__ q1,
                                            const float* __restrict__ gsum,
                                            const float* __restrict__ gsq,
                                            const float* __restrict__ gamma,
                                            const float* __restrict__ beta,
                                            const float* __restrict__ W2t,
                                            const float* __restrict__ b2,
                                            float* __restrict__ q2) {
  const int b0 = blockIdx.x * 8;
  const int t = threadIdx.x;
  __shared__ float scaleL[128], shiftL[128];
  __shared__ __align__(16) float qnL[8 * 128];

  if (t < 128) {
    float mu = gsum[t] * (1.0f / (float)B_);
    float var = gsq[t] * (1.0f / (float)B_) - mu * mu;
    float rsg = rsqrtf(var + 1e-5f) * gamma[t];
    scaleL[t] = rsg;
    shiftL[t] = beta[t] - mu * rsg;
  }
  __syncthreads();
  {
    int row = t >> 5, f4 = t & 31;
    float4 x = ((const float4*)q1)[(size_t)(b0 + row) * 32 + f4];
    x.x = x.x * scaleL[f4 * 4 + 0] + shiftL[f4 * 4 + 0];
    x.y = x.y * scaleL[f4 * 4 + 1] + shiftL[f4 * 4 + 1];
    x.z = x.z * scaleL[f4 * 4 + 2] + shiftL[f4 * 4 + 2];
    x.w = x.w * scaleL[f4 * 4 + 3] + shiftL[f4 * 4 + 3];
    ((float4*)qnL)[row * 32 + f4] = x;
  }
  __syncthreads();

  const int r = t >> 5, g4 = t & 31;
  const float4* W2t4 = (const float4*)W2t;
  float4 acc = ((const float4*)b2)[g4];
  #pragma unroll 8
  for (int f = 0; f < 128; ++f) {
    float4 w = W2t4[f * 32 + g4];
    float qv = qnL[r * 128 + f];
    acc.x += qv * w.x; acc.y += qv * w.y; acc.z += qv * w.z; acc.w += qv * w.w;
  }
  ((float4*)q2)[(size_t)(b0 + r) * 32 + g4] = acc;
}

// ---------------------------------------------------------------------------
// K4: per batch row: stage v[b] swizzled in LDS; qW[h,:] = q2-slice @ Wk_h
// (fused, Wk L2-hot); logits = qW.v + qb (/4); wave-wide softmax; out.
// grid 2048 x 256
// ---------------------------------------------------------------------------
__global__ __launch_bounds__(256) void k_attn(const float* __restrict__ v,
                                              const float* __restrict__ q2,
                                              const float* __restrict__ Wk,
                                              const float* __restrict__ bk,
                                              float* __restrict__ outp) {
  const int b = blockIdx.x;
  const int t = threadIdx.x;
  __shared__ __align__(16) float vL[64 * 128];   // XOR-swizzled float4 rows
  __shared__ __align__(16) float qWL[8 * 128];
  __shared__ __align__(16) float q2L[128];
  __shared__ float attnL[8 * 64];
  __shared__ float qbL[8];

  float4* vL4 = (float4*)vL;
  const float4* vg4 = (const float4*)(v + (size_t)b * (S_ * D_));
  #pragma unroll
  for (int i = 0; i < 8; ++i) {
    int idx = i * 256 + t;             // 2048 float4s
    int s = idx >> 5, c4 = idx & 31;
    vL4[s * 32 + (c4 ^ (s & 31))] = vg4[idx];
  }
  if (t < 32) ((float4*)q2L)[t] = ((const float4*)q2)[(size_t)b * 32 + t];
  __syncthreads();

  // qW[h,d] = sum_dk q2[h*16+dk] * Wk[h*16+dk, d]
  {
    const int h = t >> 5, d4 = t & 31;
    const float4* Wk4 = (const float4*)Wk;
    const float* q2row = &q2L[h * 16];
    float4 acc = {0.f, 0.f, 0.f, 0.f};
    #pragma unroll
    for (int dk = 0; dk < 16; ++dk) {
      float qv = q2row[dk];
      float4 w = Wk4[(h * 16 + dk) * 32 + d4];
      acc.x += qv * w.x; acc.y += qv * w.y; acc.z += qv * w.z; acc.w += qv * w.w;
    }
    ((float4*)qWL)[h * 32 + d4] = acc;
  }
  if (t < 8) {
    float acc = 0.f;
    #pragma unroll
    for (int dk = 0; dk < 16; ++dk)
      acc += q2L[t * 16 + dk] * bk[t * 16 + dk];
    qbL[t] = acc;
  }
  __syncthreads();

  // logits: thread -> (s = t&63, heads 2*hq and 2*hq+1)
  const int s = t & 63;
  const int hq = t >> 6;
  const int h0 = hq * 2, h1 = hq * 2 + 1;
  const float4* qWL4 = (const float4*)qWL;
  float a0 = 0.f, a1 = 0.f;
  #pragma unroll
  for (int d4 = 0; d4 < 32; ++d4) {
    float4 vv = vL4[s * 32 + (d4 ^ (s & 31))];
    float4 w0 = qWL4[h0 * 32 + d4];
    float4 w1 = qWL4[h1 * 32 + d4];
    a0 += vv.x * w0.x + vv.y * w0.y + vv.z * w0.z + vv.w * w0.w;
    a1 += vv.x * w1.x + vv.y * w1.y + vv.z * w1.z + vv.w * w1.w;
  }
  float l0 = (a0 + qbL[h0]) * 0.25f;   // temperature = sqrt(16) = 4
  float l1 = (a1 + qbL[h1]) * 0.25f;

  // softmax across the 64 lanes of this wave (lane == s)
  float m0 = l0, m1 = l1;
  #pragma unroll
  for (int off = 32; off; off >>= 1) {
    m0 = fmaxf(m0, __shfl_xor(m0, off, 64));
    m1 = fmaxf(m1, __shfl_xor(m1, off, 64));
  }
  float e0 = __expf(l0 - m0), e1 = __expf(l1 - m1);
  float s0 = e0, s1 = e1;
  #pragma unroll
  for (int off = 32; off; off >>= 1) {
    s0 += __shfl_xor(s0, off, 64);
    s1 += __shfl_xor(s1, off, 64);
  }
  float at0 = e0 / s0, at1 = e1 / s1;
  attnL[h0 * 64 + s] = at0;
  attnL[h1 * 64 + s] = at1;
  float* attn_out = outp + (size_t)H_ * B_ * D_;
  attn_out[(size_t)h0 * (B_ * S_) + b * S_ + s] = at0;
  attn_out[(size_t)h1 * (B_ * S_) + b * S_ + s] = at1;
  __syncthreads();

  // out[h, b, :] = sum_s attn[h,s] * v[b,s,:]; thread -> (h = t>>5, d4 = t&31)
  const int d4o = t & 31;
  const int h = t >> 5;
  float4 acc = {0.f, 0.f, 0.f, 0.f};
  #pragma unroll
  for (int si = 0; si < 64; ++si) {
    float a = attnL[h * 64 + si];
    float4 vv = vL4[si * 32 + (d4o ^ (si & 31))];
    acc.x += a * vv.x; acc.y += a * vv.y; acc.z += a * vv.z; acc.w += a * vv.w;
  }
  ((float4*)outp)[(size_t)h * (B_ * 32) + b * 32 + d4o] = acc;
}

// ---------------------------------------------------------------------------
extern "C" void kernel_launch(void* const* d_in, const int* in_sizes, int n_in,
                              void* d_out, int out_size, void* d_ws, size_t ws_size,
                              hipStream_t stream) {
  const float* v     = (const float*)d_in[0];
  const float* Wq    = (const float*)d_in[1];
  const float* bq    = (const float*)d_in[2];
  const float* gamma = (const float*)d_in[3];
  const float* beta  = (const float*)d_in[4];
  const float* W2    = (const float*)d_in[5];
  const float* b2    = (const float*)d_in[6];
  const float* Wk    = (const float*)d_in[7];
  const float* bk    = (const float*)d_in[8];

  float* ws = (float*)d_ws;
  // ws layout (floats): q1[B*F] | q2[B*F] | gsum[128] | gsq[128] | W2t[128*128]
  float* q1v  = ws;                                  // 262144
  float* q2v  = q1v + (size_t)B_ * F_;               // 262144
  float* gsum = q2v + (size_t)B_ * F_;               // 128
  float* gsq  = gsum + 128;                          // 128
  float* W2t  = gsq + 128;                           // 16384
  float* outp = (float*)d_out;

  hipLaunchKernelGGL(k_q1,     dim3(B_),  dim3(256), 0, stream, v, Wq, bq, q1v, gsum);
  hipLaunchKernelGGL(k_stats2, dim3(64),  dim3(256), 0, stream, q1v, W2, gsum, gsq, W2t);
  hipLaunchKernelGGL(k_q2,     dim3(256), dim3(256), 0, stream, q1v, gsum, gsq, gamma, beta, W2t, b2, q2v);
  hipLaunchKernelGGL(k_attn,   dim3(B_),  dim3(256), 0, stream, v, q2v, Wk, bk, outp);
}